// Round 6
// baseline (442.447 us; speedup 1.0000x reference)
//
#include <hip/hip_runtime.h>
#include <hip/hip_bf16.h>

#define BB 4096
#define DIMM 768
#define NHEADS 8
#define DHEAD 96
#define NIDS 751
#define QKSCALE 0.10206207261596577f   // 96^-0.5
#define MAXENT 1280

typedef _Float16 f16x8 __attribute__((ext_vector_type(8)));
typedef float f32x4 __attribute__((ext_vector_type(4)));

// split-f16: hi = rte(v), lo = residual (unscaled; shares one fp32 accumulator)
__device__ __forceinline__ void split2(float v, _Float16* hi, _Float16* lo) {
    _Float16 h = (_Float16)v;
    *hi = h;
    *lo = (_Float16)(v - (float)h);
}

__device__ __forceinline__ float rec2(const _Float16* hi, const _Float16* lo, size_t idx) {
    return (float)hi[idx] + (float)lo[idx];
}

__device__ __forceinline__ void gl_lds16(const void* g, void* l) {
    __builtin_amdgcn_global_load_lds(
        (const __attribute__((address_space(1))) unsigned int*)g,
        (__attribute__((address_space(3))) unsigned int*)l, 16, 0, 0);
}

// zero lsum AND out (out is gemm1's split-K atomic target)
__global__ void k_zero2(float* a, int na, float* b, int nb) {
    int i = blockIdx.x * blockDim.x + threadIdx.x;
    if (i < na) a[i] = 0.0f;
    int j = i - na;
    if (j >= 0 && j < nb) b[j] = 0.0f;
}

__global__ void k_split(const float* __restrict__ in, _Float16* __restrict__ hi,
                        _Float16* __restrict__ lo, float s, int n) {
    int i = blockIdx.x * blockDim.x + threadIdx.x;
    if (i < n) split2(in[i] * s, &hi[i], &lo[i]);
}

// W[K][N] -> Th/Tl [N][K] (scaled split), 32x32 tiles via LDS
__global__ void k_tsplit(const float* __restrict__ W, _Float16* __restrict__ Th,
                         _Float16* __restrict__ Tl, float s, int K, int N) {
    __shared__ float tile[32][33];
    int k0 = blockIdx.y * 32, n0 = blockIdx.x * 32;
    int tx = threadIdx.x, ty = threadIdx.y;
    for (int r = ty; r < 32; r += 8) tile[r][tx] = W[(size_t)(k0 + r) * N + n0 + tx];
    __syncthreads();
    for (int r = ty; r < 32; r += 8) {
        int n = n0 + r, k = k0 + tx;
        split2(tile[tx][r] * s, &Th[(size_t)n * K + k], &Tl[(size_t)n * K + k]);
    }
}

// counting sort of labels into groups + work-entry list for k_pv.
// entry = up to 8 rows (consecutive in perm) of one group.
__global__ __launch_bounds__(1024) void k_groups(
    const int* __restrict__ labels, int* __restrict__ perm,
    int* __restrict__ gstart, int* __restrict__ gcnt,
    int* __restrict__ ent_rs, int* __restrict__ ent_rc,
    int* __restrict__ ent_st, int* __restrict__ ent_cnt,
    int* __restrict__ nent) {
    __shared__ int cnt[1024], scn[1024], strt[1024], cur[1024];
    int tid = threadIdx.x;
    cnt[tid] = 0; cur[tid] = 0;
    __syncthreads();
    for (int i = tid; i < BB; i += 1024) atomicAdd(&cnt[labels[i]], 1);
    __syncthreads();
    int v = cnt[tid];
    scn[tid] = v;
    __syncthreads();
#pragma unroll
    for (int off = 1; off < 1024; off <<= 1) {
        int t = (tid >= off) ? scn[tid - off] : 0;
        __syncthreads();
        scn[tid] += t;
        __syncthreads();
    }
    int st = scn[tid] - v;   // exclusive prefix
    strt[tid] = st;
    if (tid < NIDS) { gstart[tid] = st; gcnt[tid] = v; }
    __syncthreads();
    // second scan: entry placement (ceil(cnt/8) entries per group)
    int ne = (tid < NIDS) ? ((v + 7) >> 3) : 0;
    scn[tid] = ne;
    __syncthreads();
#pragma unroll
    for (int off = 1; off < 1024; off <<= 1) {
        int t = (tid >= off) ? scn[tid - off] : 0;
        __syncthreads();
        scn[tid] += t;
        __syncthreads();
    }
    int ep = scn[tid] - ne;
    if (tid == 1023) *nent = scn[1023];
    if (tid < NIDS) {
        for (int t = 0; t < ne; t++) {
            ent_rs[ep + t] = st + t * 8;
            int rem = v - t * 8;
            ent_rc[ep + t] = rem < 8 ? rem : 8;
            ent_st[ep + t] = st;
            ent_cnt[ep + t] = v;
        }
    }
    __syncthreads();
    for (int i = tid; i < BB; i += 1024) {
        int lb = labels[i];
        int p = strt[lb] + atomicAdd(&cur[lb], 1);
        perm[p] = i;
    }
}

// C = A(M,K) * B(N,K)^T via split-f16 MFMA, 128x128 tile, BK=32, 8 waves.
// SINGLE-buffer m97 structure (32KB LDS -> 4 blocks/CU; cross-block overlap
// hides the stage drain). K-chunk via blockIdx.z (split-K for EPI 1).
// EPI 0: qkv write (n<1536 -> QK split store scaled x16; else v fp32)
// EPI 1: fp32 atomicAdd into C (split-K partials)
template <int EPI>
__global__ __launch_bounds__(512, 8) void k_gemm(
    const _Float16* __restrict__ Ah, const _Float16* __restrict__ Al, int lda,
    const _Float16* __restrict__ Bh, const _Float16* __restrict__ Bl, int ldb,
    int K, float inv,
    float* __restrict__ outF, _Float16* __restrict__ oh, _Float16* __restrict__ ol) {
    __shared__ __align__(16) _Float16 sAh[128 * 32];
    __shared__ __align__(16) _Float16 sAl[128 * 32];
    __shared__ __align__(16) _Float16 sBh[128 * 32];
    __shared__ __align__(16) _Float16 sBl[128 * 32];
    const int tid = threadIdx.x;
    const int lane = tid & 63;
    const int wave = tid >> 6;                 // 0..7
    const int wm = wave >> 2, wn = wave & 3;   // wave tile 64(m) x 32(n)
    unsigned wg = blockIdx.y * gridDim.x + blockIdx.x;
    unsigned nwg = gridDim.x * gridDim.y;
    unsigned swz = ((nwg & 7u) == 0u) ? (wg & 7u) * (nwg >> 3) + (wg >> 3) : wg;
    unsigned by = swz / gridDim.x;
    unsigned bx = swz - by * gridDim.x;
    const int m0 = by * 128, n0 = bx * 128;
    const int kbase = blockIdx.z * K;          // split-K chunk offset
    const int srow = tid >> 2;                 // 0..127
    const int scol = (tid & 3) * 8;
    const int rl = lane & 15;
    const int g8 = (lane >> 4) * 8;

    const _Float16* gAh0 = Ah + (size_t)(m0 + srow) * lda + kbase + scol;
    const _Float16* gAl0 = Al + (size_t)(m0 + srow) * lda + kbase + scol;
    const _Float16* gBh0 = Bh + (size_t)(n0 + srow) * ldb + kbase + scol;
    const _Float16* gBl0 = Bl + (size_t)(n0 + srow) * ldb + kbase + scol;
    const int d0 = tid * 8;                    // LDS dest: uniform base + lane*16B

    f32x4 acc[4][2];
    const f32x4 vzero = {0.f, 0.f, 0.f, 0.f};
#pragma unroll
    for (int a = 0; a < 4; a++)
#pragma unroll
        for (int b = 0; b < 2; b++) acc[a][b] = vzero;

    const int KS = K >> 5;
    for (int ks = 0; ks < KS; ks++) {
        __syncthreads();   // prev iteration's LDS reads done
        const int kk = ks << 5;
        gl_lds16(gAh0 + kk, &sAh[d0]);
        gl_lds16(gAl0 + kk, &sAl[d0]);
        gl_lds16(gBh0 + kk, &sBh[d0]);
        gl_lds16(gBl0 + kk, &sBl[d0]);
        __syncthreads();   // vmcnt drained: tile staged

        f16x8 ah[4], al[4], bh[2], bl[2];
#pragma unroll
        for (int t = 0; t < 4; t++) {
            ah[t] = *(const f16x8*)&sAh[(wm * 64 + t * 16 + rl) * 32 + g8];
            al[t] = *(const f16x8*)&sAl[(wm * 64 + t * 16 + rl) * 32 + g8];
        }
#pragma unroll
        for (int u = 0; u < 2; u++) {
            bh[u] = *(const f16x8*)&sBh[(wn * 32 + u * 16 + rl) * 32 + g8];
            bl[u] = *(const f16x8*)&sBl[(wn * 32 + u * 16 + rl) * 32 + g8];
        }
#pragma unroll
        for (int a = 0; a < 4; a++)
#pragma unroll
            for (int b = 0; b < 2; b++) {
                acc[a][b] = __builtin_amdgcn_mfma_f32_16x16x32_f16(ah[a], bh[b], acc[a][b], 0, 0, 0);
                acc[a][b] = __builtin_amdgcn_mfma_f32_16x16x32_f16(ah[a], bl[b], acc[a][b], 0, 0, 0);
                acc[a][b] = __builtin_amdgcn_mfma_f32_16x16x32_f16(al[a], bh[b], acc[a][b], 0, 0, 0);
            }
    }

#pragma unroll
    for (int a = 0; a < 4; a++)
#pragma unroll
        for (int b = 0; b < 2; b++) {
            f32x4 d = acc[a][b] * inv;
            int n = n0 + wn * 32 + b * 16 + rl;
            int mb = m0 + wm * 64 + a * 16 + (lane >> 4) * 4;
#pragma unroll
            for (int r = 0; r < 4; r++) {
                int m = mb + r;
                if constexpr (EPI == 0) {
                    if (n < 1536) {
                        split2(d[r] * 16.0f, &oh[(size_t)m * 1536 + n], &ol[(size_t)m * 1536 + n]);
                    } else {
                        outF[(size_t)m * DIMM + (n - 1536)] = d[r];
                    }
                } else {
                    atomicAdd(&outF[(size_t)m * DIMM + n], d[r]);
                }
            }
        }
}

// Row-sums of exp(q.k*scale), HI-ONLY. Persistent-A, SINGLE-buffer B staging
// (26.6KB LDS -> 4 blocks/CU, grid 1024 = one resident round).
__global__ __launch_bounds__(256, 4) void k_qksum(
    const _Float16* __restrict__ QKh, float* __restrict__ lsum) {
    __shared__ __align__(16) _Float16 sB[128 * 104];
    const int tid = threadIdx.x;
    const int lane = tid & 63;
    const int wave = tid >> 6;
    const int wm = wave >> 1, wn = wave & 1;
    unsigned wg = blockIdx.y * gridDim.x + blockIdx.x;   // 0..1023
    const int head = (int)(wg & 7u);                     // XCD-affine
    unsigned rest = wg >> 3;                             // 0..127
    const int m0 = (int)(rest & 31u) * 128;
    const int nq = (int)(rest >> 5);                     // 0..3 quarter of N
    const int cA = head * DHEAD;
    const int cB = DIMM + head * DHEAD;
    const int rl = lane & 15;
    const int g8 = (lane >> 4) * 8;

    // persistent A fragments (hi only): 12 x f16x8 = 48 VGPR
    f16x8 ah[3][4];
#pragma unroll
    for (int k = 0; k < 3; k++)
#pragma unroll
        for (int a = 0; a < 4; a++)
            ah[k][a] = *(const f16x8*)(QKh +
                (size_t)(m0 + wm * 64 + a * 16 + rl) * 1536 + cA + k * 32 + g8);

    const f32x4 vzero = {0.f, 0.f, 0.f, 0.f};
    f32x4 es[4];
#pragma unroll
    for (int a = 0; a < 4; a++) es[a] = vzero;
    const float esc = QKSCALE * (1.0f / 256.0f);

    for (int nt = 0; nt < 8; nt++) {
        __syncthreads();   // prev tile's reads done
        const int n0 = (nq * 8 + nt) * 128;
#pragma unroll
        for (int rd = 0; rd < 7; rd++) {
            int idx = rd * 256 + tid;
            if (idx < 1664) {                 // 128 rows x 13 granules
                int row = idx / 13;
                int c = idx - row * 13;
                int col = (c < 12) ? c * 8 : 0;   // pad granule: safe garbage
                gl_lds16(QKh + (size_t)(n0 + row) * 1536 + cB + col,
                         &sB[idx * 8]);
            }
        }
        __syncthreads();   // vmcnt drained

        f32x4 acc[4][4];
#pragma unroll
        for (int a = 0; a < 4; a++)
#pragma unroll
            for (int b = 0; b < 4; b++) acc[a][b] = vzero;
#pragma unroll
        for (int k = 0; k < 3; k++) {
            f16x8 bh[4];
#pragma unroll
            for (int b = 0; b < 4; b++)
                bh[b] = *(const f16x8*)&sB[(wn * 64 + b * 16 + rl) * 104 + k * 32 + g8];
#pragma unroll
            for (int a = 0; a < 4; a++)
#pragma unroll
                for (int b = 0; b < 4; b++)
                    acc[a][b] = __builtin_amdgcn_mfma_f32_16x16x32_f16(ah[k][a], bh[b], acc[a][b], 0, 0, 0);
        }
#pragma unroll
        for (int a = 0; a < 4; a++)
#pragma unroll
            for (int b = 0; b < 4; b++)
#pragma unroll
                for (int r = 0; r < 4; r++)
                    es[a][r] += __expf(acc[a][b][r] * esc);
    }

    // once-per-block transpose-reduce; red aliased onto sB
    __syncthreads();
    float (*red)[33] = (float (*)[33])&sB[0];
#pragma unroll
    for (int a = 0; a < 4; a++) {
        int rb = wm * 64 + a * 16 + (lane >> 4) * 4;
#pragma unroll
        for (int r = 0; r < 4; r++) red[rb + r][wn * 16 + rl] = es[a][r];
    }
    __syncthreads();
    if (tid < 128) {
        float s = 0.f;
#pragma unroll
        for (int c = 0; c < 32; c++) s += red[tid][c];
        atomicAdd(&lsum[(size_t)head * BB + m0 + tid], s);
    }
}

// masked PV, per-group-entry blocks: entry = up to 8 rows of one group.
// Group K-sections (~17KB) go L1-hot after the first row; V rows read once
// per chunk for all rows of the entry.
__global__ __launch_bounds__(256) void k_pv(
    const _Float16* __restrict__ QKh, const _Float16* __restrict__ QKl,
    const float* __restrict__ vbuf, const float* __restrict__ lsum,
    const int* __restrict__ perm,
    const int* __restrict__ ent_rs, const int* __restrict__ ent_rc,
    const int* __restrict__ ent_st, const int* __restrict__ ent_cnt,
    const int* __restrict__ nent,
    _Float16* __restrict__ oh, _Float16* __restrict__ ol) {
    const int e = blockIdx.x;
    if (e >= *nent) return;
    const int rs = ent_rs[e], rc = ent_rc[e];
    const int st = ent_st[e], cnt = ent_cnt[e];
    const int tid = threadIdx.x;
    const int wave = tid >> 6;
    const int lane = tid & 63;
    __shared__ float wv[8][NHEADS][32];
    __shared__ int pidx[32];
    __shared__ int rowi[8];
    if (tid < rc) rowi[tid] = perm[rs + tid];
    const float esc = QKSCALE * (1.0f / 256.0f);
    const int c1 = tid + 256, c2 = tid + 512;
    const int h0 = tid / DHEAD, h1 = c1 / DHEAD, h2 = c2 / DHEAD;
    float a0[8], a1[8], a2[8];
#pragma unroll
    for (int ii = 0; ii < 8; ii++) { a0[ii] = 0.f; a1[ii] = 0.f; a2[ii] = 0.f; }
    __syncthreads();

    for (int jb = 0; jb < cnt; jb += 32) {
        int ch = cnt - jb; if (ch > 32) ch = 32;
        __syncthreads();
        if (tid < ch) pidx[tid] = perm[st + jb + tid];
        __syncthreads();
        // phase 1: tasks (row ii, head h) strided over 4 waves; inner loop j
        for (int t = wave; t < rc * NHEADS; t += 4) {
            int ii = t >> 3, h = t & 7;
            int i = rowi[ii];
            size_t qb = (size_t)i * 1536 + h * DHEAD;
            float q0 = rec2(QKh, QKl, qb + lane);
            float q1 = (lane < 32) ? rec2(QKh, QKl, qb + 64 + lane) : 0.f;
            float invl = 1.0f / lsum[(size_t)h * BB + i];
            for (int jj = 0; jj < ch; jj++) {
                size_t kb = (size_t)pidx[jj] * 1536 + DIMM + h * DHEAD;
                float p = q0 * rec2(QKh, QKl, kb + lane);
                if (lane < 32) p += q1 * rec2(QKh, QKl, kb + 64 + lane);
#pragma unroll
                for (int m = 32; m >= 1; m >>= 1) p += __shfl_xor(p, m);
                if (lane == 0) wv[ii][h][jj] = __expf(p * esc) * invl;
            }
        }
        __syncthreads();
        // phase 2: V accumulation; v row read once for all entry rows
        for (int jj = 0; jj < ch; jj++) {
            const float* vr = vbuf + (size_t)pidx[jj] * DIMM;
            float v0 = vr[tid], v1 = vr[c1], v2 = vr[c2];
#pragma unroll
            for (int ii = 0; ii < 8; ii++) {
                if (ii >= rc) break;
                a0[ii] += wv[ii][h0][jj] * v0;
                a1[ii] += wv[ii][h1][jj] * v1;
                a2[ii] += wv[ii][h2][jj] * v2;
            }
        }
    }
#pragma unroll
    for (int ii = 0; ii < 8; ii++) {
        if (ii >= rc) break;
        size_t ob = (size_t)rowi[ii] * DIMM;
        split2(a0[ii] * 16.0f, &oh[ob + tid], &ol[ob + tid]);
        split2(a1[ii] * 16.0f, &oh[ob + c1], &ol[ob + c1]);
        split2(a2[ii] * 16.0f, &oh[ob + c2], &ol[ob + c2]);
    }
}

extern "C" void kernel_launch(void* const* d_in, const int* in_sizes, int n_in,
                              void* d_out, int out_size, void* d_ws, size_t ws_size,
                              hipStream_t stream) {
    const float* x = (const float*)d_in[0];
    const int* labels = (const int*)d_in[1];
    const float* Wqkv = (const float*)d_in[2];
    const float* Wout = (const float*)d_in[3];
    float* out = (float*)d_out;

    char* ws = (char*)d_ws;
    size_t off = 0;
    auto alloc = [&](size_t bytes) -> void* {
        void* p = ws + off;
        off += (bytes + 255) & ~(size_t)255;
        return p;
    };
    _Float16* Xh   = (_Float16*)alloc((size_t)BB * DIMM * 2);
    _Float16* Xl   = (_Float16*)alloc((size_t)BB * DIMM * 2);
    _Float16* WqTh = (_Float16*)alloc((size_t)2304 * DIMM * 2);
    _Float16* WqTl = (_Float16*)alloc((size_t)2304 * DIMM * 2);
    _Float16* WoTh = (_Float16*)alloc((size_t)DIMM * DIMM * 2);
    _Float16* WoTl = (_Float16*)alloc((size_t)DIMM * DIMM * 2);
    _Float16* QKh  = (_Float16*)alloc((size_t)BB * 1536 * 2);
    _Float16* QKl  = (_Float16*)alloc((size_t)BB * 1536 * 2);
    float* vbuf    = (float*)alloc((size_t)BB * DIMM * 4);
    float* lsum    = (float*)alloc((size_t)NHEADS * BB * 4);
    _Float16* Oh   = (_Float16*)alloc((size_t)BB * DIMM * 2);
    _Float16* Ol   = (_Float16*)alloc((size_t)BB * DIMM * 2);
    int* perm      = (int*)alloc(BB * 4);
    int* gstart    = (int*)alloc(1024 * 4);
    int* gcnt      = (int*)alloc(1024 * 4);
    int* ent_rs    = (int*)alloc(MAXENT * 4);
    int* ent_rc    = (int*)alloc(MAXENT * 4);
    int* ent_st    = (int*)alloc(MAXENT * 4);
    int* ent_cnt   = (int*)alloc(MAXENT * 4);
    int* nent      = (int*)alloc(256);

    const int nz = NHEADS * BB + BB * DIMM;   // lsum + out
    k_zero2<<<dim3((nz + 255) / 256), dim3(256), 0, stream>>>(lsum, NHEADS * BB, out, BB * DIMM);
    k_split<<<dim3((BB * DIMM + 255) / 256), dim3(256), 0, stream>>>(x, Xh, Xl, 16.0f, BB * DIMM);
    k_tsplit<<<dim3(2304 / 32, DIMM / 32), dim3(32, 8), 0, stream>>>(Wqkv, WqTh, WqTl, 256.0f, DIMM, 2304);
    k_tsplit<<<dim3(DIMM / 32, DIMM / 32), dim3(32, 8), 0, stream>>>(Wout, WoTh, WoTl, 256.0f, DIMM, DIMM);
    k_groups<<<dim3(1), dim3(1024), 0, stream>>>(labels, perm, gstart, gcnt,
                                                 ent_rs, ent_rc, ent_st, ent_cnt, nent);

    // qkv = x @ Wqkv : A scale 16, B scale 256 -> inv 1/4096
    k_gemm<0><<<dim3(2304 / 128, BB / 128, 1), dim3(512), 0, stream>>>(
        Xh, Xl, DIMM, WqTh, WqTl, DIMM, DIMM, 1.0f / 4096.0f, vbuf, QKh, QKl);
    // row sums of exp(q.k * scale), hi-only
    k_qksum<<<dim3(32, 32), dim3(256), 0, stream>>>(QKh, lsum);
    // masked PV over group entries
    k_pv<<<dim3(MAXENT), dim3(256), 0, stream>>>(QKh, QKl, vbuf, lsum, perm,
                                                 ent_rs, ent_rc, ent_st, ent_cnt, nent, Oh, Ol);
    // out = O @ Wout : split-K x4, atomic fp32 epilogue
    k_gemm<1><<<dim3(DIMM / 128, BB / 128, 4), dim3(512), 0, stream>>>(
        Oh, Ol, DIMM, WoTh, WoTl, DIMM, 192, 1.0f / 4096.0f, out, nullptr, nullptr);
}

// Round 7
// 294.967 us; speedup vs baseline: 1.5000x; 1.5000x over previous
//
#include <hip/hip_runtime.h>
#include <hip/hip_bf16.h>

#define BB 4096
#define DIMM 768
#define NHEADS 8
#define DHEAD 96
#define NIDS 751
#define QKSCALE 0.10206207261596577f   // 96^-0.5
#define PVCH 96

typedef _Float16 f16x8 __attribute__((ext_vector_type(8)));
typedef float f32x4 __attribute__((ext_vector_type(4)));

// split-f16: hi = rte(v), lo = residual (unscaled; shares one fp32 accumulator)
__device__ __forceinline__ void split2(float v, _Float16* hi, _Float16* lo) {
    _Float16 h = (_Float16)v;
    *hi = h;
    *lo = (_Float16)(v - (float)h);
}

__device__ __forceinline__ float rec2(const _Float16* hi, const _Float16* lo, size_t idx) {
    return (float)hi[idx] + (float)lo[idx];
}

__device__ __forceinline__ void gl_lds16(const void* g, void* l) {
    __builtin_amdgcn_global_load_lds(
        (const __attribute__((address_space(1))) unsigned int*)g,
        (__attribute__((address_space(3))) unsigned int*)l, 16, 0, 0);
}

// zero lsum AND out (out is gemm1's split-K atomic target)
__global__ void k_zero2(float* a, int na, float* b, int nb) {
    int i = blockIdx.x * blockDim.x + threadIdx.x;
    if (i < na) a[i] = 0.0f;
    int j = i - na;
    if (j >= 0 && j < nb) b[j] = 0.0f;
}

__global__ void k_split(const float* __restrict__ in, _Float16* __restrict__ hi,
                        _Float16* __restrict__ lo, float s, int n) {
    int i = blockIdx.x * blockDim.x + threadIdx.x;
    if (i < n) split2(in[i] * s, &hi[i], &lo[i]);
}

// W[K][N] -> Th/Tl [N][K] (scaled split), 32x32 tiles via LDS
__global__ void k_tsplit(const float* __restrict__ W, _Float16* __restrict__ Th,
                         _Float16* __restrict__ Tl, float s, int K, int N) {
    __shared__ float tile[32][33];
    int k0 = blockIdx.y * 32, n0 = blockIdx.x * 32;
    int tx = threadIdx.x, ty = threadIdx.y;
    for (int r = ty; r < 32; r += 8) tile[r][tx] = W[(size_t)(k0 + r) * N + n0 + tx];
    __syncthreads();
    for (int r = ty; r < 32; r += 8) {
        int n = n0 + r, k = k0 + tx;
        split2(tile[tx][r] * s, &Th[(size_t)n * K + k], &Tl[(size_t)n * K + k]);
    }
}

// counting sort of labels into groups; single block, parallel Hillis-Steele scan
__global__ __launch_bounds__(1024) void k_groups(
    const int* __restrict__ labels, int* __restrict__ perm,
    int* __restrict__ gstart, int* __restrict__ gcnt) {
    __shared__ int cnt[1024], scn[1024], strt[1024], cur[1024];
    int tid = threadIdx.x;
    cnt[tid] = 0; cur[tid] = 0;
    __syncthreads();
    for (int i = tid; i < BB; i += 1024) atomicAdd(&cnt[labels[i]], 1);
    __syncthreads();
    int v = cnt[tid];
    scn[tid] = v;
    __syncthreads();
#pragma unroll
    for (int off = 1; off < 1024; off <<= 1) {
        int t = (tid >= off) ? scn[tid - off] : 0;
        __syncthreads();
        scn[tid] += t;
        __syncthreads();
    }
    int st = scn[tid] - v;   // exclusive prefix
    strt[tid] = st;
    if (tid < NIDS) { gstart[tid] = st; gcnt[tid] = v; }
    __syncthreads();
    for (int i = tid; i < BB; i += 1024) {
        int lb = labels[i];
        int p = strt[lb] + atomicAdd(&cur[lb], 1);
        perm[p] = i;
    }
}

// C = A(M,K) * B(N,K)^T via split-f16 MFMA, 128x128 tile, BK=32, 8 waves (512 thr).
// 2-phase prefetch; K-chunk via blockIdx.z (split-K for EPI 1, atomicAdd epilogue).
// EPI 0: qkv write (n<1536 -> QK split store scaled x16; else v fp32)
// EPI 1: fp32 atomicAdd into C (split-K partials)
template <int EPI>
__global__ __launch_bounds__(512, 4) void k_gemm(
    const _Float16* __restrict__ Ah, const _Float16* __restrict__ Al, int lda,
    const _Float16* __restrict__ Bh, const _Float16* __restrict__ Bl, int ldb,
    int K, float inv,
    float* __restrict__ outF, _Float16* __restrict__ oh, _Float16* __restrict__ ol) {
    __shared__ __align__(16) _Float16 sAh[2][128 * 32];
    __shared__ __align__(16) _Float16 sAl[2][128 * 32];
    __shared__ __align__(16) _Float16 sBh[2][128 * 32];
    __shared__ __align__(16) _Float16 sBl[2][128 * 32];
    const int tid = threadIdx.x;
    const int lane = tid & 63;
    const int wave = tid >> 6;           // 0..7
    const int wm = wave >> 2, wn = wave & 3;   // wave tile 64(m) x 32(n)
    // bijective XCD-chunked swizzle within a z-slice (nwg per slice % 8 == 0)
    unsigned wg = blockIdx.y * gridDim.x + blockIdx.x;
    unsigned nwg = gridDim.x * gridDim.y;
    unsigned swz = ((nwg & 7u) == 0u) ? (wg & 7u) * (nwg >> 3) + (wg >> 3) : wg;
    unsigned by = swz / gridDim.x;
    unsigned bx = swz - by * gridDim.x;
    const int m0 = by * 128, n0 = bx * 128;
    const int kbase = blockIdx.z * K;    // split-K chunk offset
    const int srow = tid >> 2;           // 0..127, one staging round
    const int scol = (tid & 3) * 8;
    const int rl = lane & 15;
    const int g8 = (lane >> 4) * 8;

    const _Float16* gAh0 = Ah + (size_t)(m0 + srow) * lda + kbase + scol;
    const _Float16* gAl0 = Al + (size_t)(m0 + srow) * lda + kbase + scol;
    const _Float16* gBh0 = Bh + (size_t)(n0 + srow) * ldb + kbase + scol;
    const _Float16* gBl0 = Bl + (size_t)(n0 + srow) * ldb + kbase + scol;
    const int d0 = tid * 8;              // LDS dest: wave-uniform base + lane*16B

    auto stage = [&](int b, int kk) {
        gl_lds16(gAh0 + kk, &sAh[b][d0]);
        gl_lds16(gAl0 + kk, &sAl[b][d0]);
        gl_lds16(gBh0 + kk, &sBh[b][d0]);
        gl_lds16(gBl0 + kk, &sBl[b][d0]);
    };

    f32x4 acc[4][2];
    const f32x4 vzero = {0.f, 0.f, 0.f, 0.f};
#pragma unroll
    for (int a = 0; a < 4; a++)
#pragma unroll
        for (int b = 0; b < 2; b++) acc[a][b] = vzero;

    const int KS = K >> 5;
    stage(0, 0);
    for (int ks = 0; ks < KS; ks++) {
        __syncthreads();   // buf[ks&1] staged; prev reads drained
        if (ks + 1 < KS) stage((ks + 1) & 1, (ks + 1) << 5);
        const int cb = ks & 1;
        f16x8 ah[4], al[4], bh[2], bl[2];
#pragma unroll
        for (int t = 0; t < 4; t++) {
            ah[t] = *(const f16x8*)&sAh[cb][(wm * 64 + t * 16 + rl) * 32 + g8];
            al[t] = *(const f16x8*)&sAl[cb][(wm * 64 + t * 16 + rl) * 32 + g8];
        }
#pragma unroll
        for (int u = 0; u < 2; u++) {
            bh[u] = *(const f16x8*)&sBh[cb][(wn * 32 + u * 16 + rl) * 32 + g8];
            bl[u] = *(const f16x8*)&sBl[cb][(wn * 32 + u * 16 + rl) * 32 + g8];
        }
#pragma unroll
        for (int a = 0; a < 4; a++)
#pragma unroll
            for (int b = 0; b < 2; b++) {
                acc[a][b] = __builtin_amdgcn_mfma_f32_16x16x32_f16(ah[a], bh[b], acc[a][b], 0, 0, 0);
                acc[a][b] = __builtin_amdgcn_mfma_f32_16x16x32_f16(ah[a], bl[b], acc[a][b], 0, 0, 0);
                acc[a][b] = __builtin_amdgcn_mfma_f32_16x16x32_f16(al[a], bh[b], acc[a][b], 0, 0, 0);
            }
    }

#pragma unroll
    for (int a = 0; a < 4; a++)
#pragma unroll
        for (int b = 0; b < 2; b++) {
            f32x4 d = acc[a][b] * inv;
            int n = n0 + wn * 32 + b * 16 + rl;
            int mb = m0 + wm * 64 + a * 16 + (lane >> 4) * 4;
#pragma unroll
            for (int r = 0; r < 4; r++) {
                int m = mb + r;
                if constexpr (EPI == 0) {
                    if (n < 1536) {
                        split2(d[r] * 16.0f, &oh[(size_t)m * 1536 + n], &ol[(size_t)m * 1536 + n]);
                    } else {
                        outF[(size_t)m * DIMM + (n - 1536)] = d[r];
                    }
                } else {
                    atomicAdd(&outF[(size_t)m * DIMM + n], d[r]);
                }
            }
        }
}

// Row-sums of exp(q.k*scale), HI-ONLY (denominator averages 4096 independent
// per-term errors -> relative error ~1e-6; numerator path in k_pv stays split).
// Persistent-A + double-buffered B staging (2-phase prefetch), red aliased on sB.
// Grid 1024: wg&7 = head (XCD-affine), each block sweeps 8 N-tiles of 128.
__global__ __launch_bounds__(256) void k_qksum(
    const _Float16* __restrict__ QKh, float* __restrict__ lsum) {
    __shared__ __align__(16) _Float16 sB[2][128 * 104];
    const int tid = threadIdx.x;
    const int lane = tid & 63;
    const int wave = tid >> 6;
    const int wm = wave >> 1, wn = wave & 1;
    unsigned wg = blockIdx.y * gridDim.x + blockIdx.x;   // 0..1023
    const int head = (int)(wg & 7u);                     // XCD-affine
    unsigned rest = wg >> 3;                             // 0..127
    const int m0 = (int)(rest & 31u) * 128;
    const int nq = (int)(rest >> 5);                     // 0..3 quarter of N
    const int cA = head * DHEAD;
    const int cB = DIMM + head * DHEAD;
    const int rl = lane & 15;
    const int g8 = (lane >> 4) * 8;

    // persistent A fragments (hi only): 12 x f16x8 = 48 VGPR
    f16x8 ah[3][4];
#pragma unroll
    for (int k = 0; k < 3; k++)
#pragma unroll
        for (int a = 0; a < 4; a++)
            ah[k][a] = *(const f16x8*)(QKh +
                (size_t)(m0 + wm * 64 + a * 16 + rl) * 1536 + cA + k * 32 + g8);

    auto stage = [&](int b, int tile) {
        const int n0 = tile * 128;
#pragma unroll
        for (int rd = 0; rd < 7; rd++) {
            int idx = rd * 256 + tid;
            if (idx < 1664) {                 // 128 rows x 13 granules
                int row = idx / 13;
                int c = idx - row * 13;
                int col = (c < 12) ? c * 8 : 0;   // pad granule: safe garbage
                gl_lds16(QKh + (size_t)(n0 + row) * 1536 + cB + col,
                         &sB[b][idx * 8]);    // dest linear = base + lane*16B
            }
        }
    };

    const f32x4 vzero = {0.f, 0.f, 0.f, 0.f};
    f32x4 es[4];
#pragma unroll
    for (int a = 0; a < 4; a++) es[a] = vzero;
    const float esc = QKSCALE * (1.0f / 256.0f);

    stage(0, nq * 8);
    for (int nt = 0; nt < 8; nt++) {
        __syncthreads();   // buf[nt&1] ready; prev reads drained
        if (nt < 7) stage((nt + 1) & 1, nq * 8 + nt + 1);
        const int cb = nt & 1;
        f32x4 acc[4][4];
#pragma unroll
        for (int a = 0; a < 4; a++)
#pragma unroll
            for (int b = 0; b < 4; b++) acc[a][b] = vzero;
#pragma unroll
        for (int k = 0; k < 3; k++) {
            f16x8 bh[4];
#pragma unroll
            for (int b = 0; b < 4; b++)
                bh[b] = *(const f16x8*)&sB[cb][(wn * 64 + b * 16 + rl) * 104 + k * 32 + g8];
#pragma unroll
            for (int a = 0; a < 4; a++)
#pragma unroll
                for (int b = 0; b < 4; b++)
                    acc[a][b] = __builtin_amdgcn_mfma_f32_16x16x32_f16(ah[k][a], bh[b], acc[a][b], 0, 0, 0);
        }
#pragma unroll
        for (int a = 0; a < 4; a++)
#pragma unroll
            for (int b = 0; b < 4; b++)
#pragma unroll
                for (int r = 0; r < 4; r++)
                    es[a][r] += __expf(acc[a][b][r] * esc);
    }

    // once-per-block transpose-reduce; red aliased onto sB[0]
    float (*red)[33] = (float (*)[33])&sB[0][0];
#pragma unroll
    for (int a = 0; a < 4; a++) {
        int rb = wm * 64 + a * 16 + (lane >> 4) * 4;
#pragma unroll
        for (int r = 0; r < 4; r++) red[rb + r][wn * 16 + rl] = es[a][r];
    }
    __syncthreads();
    if (tid < 128) {
        float s = 0.f;
#pragma unroll
        for (int c = 0; c < 32; c++) s += red[tid][c];
        atomicAdd(&lsum[(size_t)head * BB + m0 + tid], s);
    }
}

// masked PV: 4096 blocks ordered by SORTED position (perm) with XCD-chunked
// swizzle -> same-group rows co-resident on one XCD, K/V gathers hit L2.
// Phase 1: STATIC head loop (q regs, rule #20), jj strided over 4 waves.
// Phase 2: 3 static passes accumulate O[i][0..767].
__global__ __launch_bounds__(256) void k_pv(
    const _Float16* __restrict__ QKh, const _Float16* __restrict__ QKl,
    const float* __restrict__ vbuf, const float* __restrict__ lsum,
    const int* __restrict__ labels, const int* __restrict__ perm,
    const int* __restrict__ gstart, const int* __restrict__ gcnt,
    _Float16* __restrict__ oh, _Float16* __restrict__ ol) {
    unsigned bsw = (blockIdx.x & 7u) * 512u + (blockIdx.x >> 3);   // 4096 = 8*512
    const int i = perm[bsw];          // sorted order -> group-local L2 reuse
    const int tid = threadIdx.x;
    const int wave = tid >> 6;
    const int lane = tid & 63;
    __shared__ float wv[NHEADS][PVCH];
    __shared__ int pidx[PVCH];
    const int lab = labels[i];
    const int st = gstart[lab];
    const int cnt = gcnt[lab];
    const float esc = QKSCALE * (1.0f / 256.0f);

    // preload Q (all heads) + inverse denominators — all statically indexed
    float q0[NHEADS], q1[NHEADS], invl[NHEADS];
#pragma unroll
    for (int h = 0; h < NHEADS; h++) {
        size_t base = (size_t)i * 1536 + h * DHEAD;
        q0[h] = rec2(QKh, QKl, base + lane);
        q1[h] = (lane < 32) ? rec2(QKh, QKl, base + 64 + lane) : 0.0f;
        invl[h] = 1.0f / lsum[(size_t)h * BB + i];
    }
    const int d1 = tid + 256, d2 = tid + 512;
    const int h0 = tid / DHEAD, h1 = d1 / DHEAD, h2 = d2 / DHEAD;
    float acc0 = 0.f, acc1 = 0.f, acc2 = 0.f;

    for (int b0 = 0; b0 < cnt; b0 += PVCH) {
        int ch = cnt - b0; if (ch > PVCH) ch = PVCH;
        __syncthreads();
        if (tid < ch) pidx[tid] = perm[st + b0 + tid];
        __syncthreads();
        // phase 1: static head loop (q0[hh] compile-time indexed -> registers)
#pragma unroll
        for (int hh = 0; hh < NHEADS; hh++) {
            for (int jj = wave; jj < ch; jj += 4) {
                size_t kb = (size_t)pidx[jj] * 1536 + DIMM + hh * DHEAD;
                float p = q0[hh] * rec2(QKh, QKl, kb + lane);
                if (lane < 32) p += q1[hh] * rec2(QKh, QKl, kb + 64 + lane);
#pragma unroll
                for (int m = 32; m >= 1; m >>= 1) p += __shfl_xor(p, m);
                if (lane == 0) wv[hh][jj] = __expf(p * esc) * invl[hh];
            }
        }
        __syncthreads();
        // phase 2: V accumulation, 3 passes x 256 threads
        for (int jj = 0; jj < ch; jj++) {
            const float* vr = vbuf + (size_t)pidx[jj] * DIMM;
            acc0 += wv[h0][jj] * vr[tid];
            acc1 += wv[h1][jj] * vr[d1];
            acc2 += wv[h2][jj] * vr[d2];
        }
    }
    size_t ob = (size_t)i * DIMM;
    split2(acc0 * 16.0f, &oh[ob + tid], &ol[ob + tid]);
    split2(acc1 * 16.0f, &oh[ob + d1], &ol[ob + d1]);
    split2(acc2 * 16.0f, &oh[ob + d2], &ol[ob + d2]);
}

extern "C" void kernel_launch(void* const* d_in, const int* in_sizes, int n_in,
                              void* d_out, int out_size, void* d_ws, size_t ws_size,
                              hipStream_t stream) {
    const float* x = (const float*)d_in[0];
    const int* labels = (const int*)d_in[1];
    const float* Wqkv = (const float*)d_in[2];
    const float* Wout = (const float*)d_in[3];
    float* out = (float*)d_out;

    char* ws = (char*)d_ws;
    size_t off = 0;
    auto alloc = [&](size_t bytes) -> void* {
        void* p = ws + off;
        off += (bytes + 255) & ~(size_t)255;
        return p;
    };
    _Float16* Xh   = (_Float16*)alloc((size_t)BB * DIMM * 2);
    _Float16* Xl   = (_Float16*)alloc((size_t)BB * DIMM * 2);
    _Float16* WqTh = (_Float16*)alloc((size_t)2304 * DIMM * 2);
    _Float16* WqTl = (_Float16*)alloc((size_t)2304 * DIMM * 2);
    _Float16* WoTh = (_Float16*)alloc((size_t)DIMM * DIMM * 2);
    _Float16* WoTl = (_Float16*)alloc((size_t)DIMM * DIMM * 2);
    _Float16* QKh  = (_Float16*)alloc((size_t)BB * 1536 * 2);
    _Float16* QKl  = (_Float16*)alloc((size_t)BB * 1536 * 2);
    float* vbuf    = (float*)alloc((size_t)BB * DIMM * 4);
    float* lsum    = (float*)alloc((size_t)NHEADS * BB * 4);
    _Float16* Oh   = (_Float16*)alloc((size_t)BB * DIMM * 2);
    _Float16* Ol   = (_Float16*)alloc((size_t)BB * DIMM * 2);
    int* perm      = (int*)alloc(BB * 4);
    int* gstart    = (int*)alloc(1024 * 4);
    int* gcnt      = (int*)alloc(1024 * 4);

    const int nz = NHEADS * BB + BB * DIMM;   // lsum + out
    k_zero2<<<dim3((nz + 255) / 256), dim3(256), 0, stream>>>(lsum, NHEADS * BB, out, BB * DIMM);
    k_split<<<dim3((BB * DIMM + 255) / 256), dim3(256), 0, stream>>>(x, Xh, Xl, 16.0f, BB * DIMM);
    k_tsplit<<<dim3(2304 / 32, DIMM / 32), dim3(32, 8), 0, stream>>>(Wqkv, WqTh, WqTl, 256.0f, DIMM, 2304);
    k_tsplit<<<dim3(DIMM / 32, DIMM / 32), dim3(32, 8), 0, stream>>>(Wout, WoTh, WoTl, 256.0f, DIMM, DIMM);
    k_groups<<<dim3(1), dim3(1024), 0, stream>>>(labels, perm, gstart, gcnt);

    // qkv = x @ Wqkv : A scale 16, B scale 256 -> inv 1/4096
    k_gemm<0><<<dim3(2304 / 128, BB / 128, 1), dim3(512), 0, stream>>>(
        Xh, Xl, DIMM, WqTh, WqTl, DIMM, DIMM, 1.0f / 4096.0f, vbuf, QKh, QKl);
    // row sums of exp(q.k * scale), hi-only
    k_qksum<<<dim3(32, 32), dim3(256), 0, stream>>>(QKh, lsum);
    // masked PV (perm-ordered blocks)
    k_pv<<<dim3(BB), dim3(256), 0, stream>>>(QKh, QKl, vbuf, lsum, labels, perm, gstart, gcnt, Oh, Ol);
    // out = O @ Wout : split-K x2, atomic fp32 epilogue
    k_gemm<1><<<dim3(DIMM / 128, BB / 128, 2), dim3(512), 0, stream>>>(
        Oh, Ol, DIMM, WoTh, WoTl, DIMM, 384, 1.0f / 4096.0f, out, nullptr, nullptr);
}